// Round 5
// baseline (588.242 us; speedup 1.0000x reference)
//
#include <hip/hip_runtime.h>
#include <math.h>

#define NSLOPE 0.2f
#define CAP 4096          // max edges per 64-node bucket handled in LDS

__device__ __forceinline__ float2 nt_load_f2(const float2* p) {
    union { unsigned long long u; float2 f; } c;
    c.u = __builtin_nontemporal_load((const unsigned long long*)p);
    return c.f;
}

// ---------------- K0: zero degree counters ----------------
__global__ __launch_bounds__(256) void k0_zero(int* __restrict__ deg, int n) {
    int i = blockIdx.x * 256 + threadIdx.x;
    if (i < n) deg[i] = 0;
}

// ---------------- K1: h = feat @ W_fc, fused pp = h @ W_post + b_post ----------------
__global__ __launch_bounds__(256) void k1_proj(
    const float* __restrict__ feat, const float* __restrict__ wfc,
    const float* __restrict__ wpost, const float* __restrict__ bpost,
    float* __restrict__ h, float4* __restrict__ pp, int n)
{
    __shared__ float wfc_s[128 * 64];   // 32 KB
    __shared__ float feat_s[16 * 128];  // 8 KB
    int t = threadIdx.x;
    for (int i = t; i < 128 * 64 / 4; i += 256)
        ((float4*)wfc_s)[i] = ((const float4*)wfc)[i];
    int row0 = blockIdx.x * 16;
    {
        const float4* fv = (const float4*)(feat + (long)row0 * 128);
        int lim = (n - row0) * (128 / 4);
        if (lim > 16 * 128 / 4) lim = 16 * 128 / 4;
        for (int i = t; i < lim; i += 256)
            ((float4*)feat_s)[i] = fv[i];
    }
    __syncthreads();
    int lane = t & 63, wv = t >> 6;
    const float* fr = feat_s + wv * 4 * 128;
    float acc[4] = {0.f, 0.f, 0.f, 0.f};
    #pragma unroll 2
    for (int k = 0; k < 128; k += 4) {
        float w0 = wfc_s[(k + 0) * 64 + lane];
        float w1 = wfc_s[(k + 1) * 64 + lane];
        float w2 = wfc_s[(k + 2) * 64 + lane];
        float w3 = wfc_s[(k + 3) * 64 + lane];
        #pragma unroll
        for (int r = 0; r < 4; r++) {
            float4 f = *(const float4*)(fr + r * 128 + k);  // b128 broadcast
            acc[r] += f.x * w0 + f.y * w1 + f.z * w2 + f.w * w3;
        }
    }
    int r0 = row0 + wv * 4;
    #pragma unroll
    for (int r = 0; r < 4; r++)
        if (r0 + r < n) h[(long)(r0 + r) * 64 + lane] = acc[r];
    float4 wp = ((const float4*)wpost)[lane];
    float4 bp = *((const float4*)bpost);
    #pragma unroll
    for (int r = 0; r < 4; r++) {
        float cx = acc[r] * wp.x, cy = acc[r] * wp.y,
              cz = acc[r] * wp.z, cw = acc[r] * wp.w;
        #pragma unroll
        for (int off = 32; off > 0; off >>= 1) {
            cx += __shfl_down(cx, off);
            cy += __shfl_down(cy, off);
            cz += __shfl_down(cz, off);
            cw += __shfl_down(cw, off);
        }
        if (lane == 0 && r0 + r < n) {
            float4 o;
            o.x = cx + bp.x; o.y = cy + bp.y; o.z = cz + bp.z; o.w = cw + bp.w;
            pp[r0 + r] = o;
        }
    }
}

// ---------------- K2: degree histogram over dst ----------------
__global__ __launch_bounds__(256) void k2_hist(const int* __restrict__ dst,
                                               int* __restrict__ deg, int E) {
    int e = blockIdx.x * 256 + threadIdx.x;
    if (e < E) atomicAdd(&deg[dst[e]], 1);
}

// ---------------- scan: exclusive prefix of deg -> base ----------------
__global__ __launch_bounds__(256) void scan_a(const int* __restrict__ deg,
                                              int* __restrict__ base,
                                              int* __restrict__ bsum, int N) {
    __shared__ int lds[256];
    int t = threadIdx.x;
    int i0 = blockIdx.x * 1024 + t * 4;
    int d0 = (i0 + 0 < N) ? deg[i0 + 0] : 0;
    int d1 = (i0 + 1 < N) ? deg[i0 + 1] : 0;
    int d2 = (i0 + 2 < N) ? deg[i0 + 2] : 0;
    int d3 = (i0 + 3 < N) ? deg[i0 + 3] : 0;
    lds[t] = d0 + d1 + d2 + d3;
    __syncthreads();
    for (int off = 1; off < 256; off <<= 1) {
        int v = (t >= off) ? lds[t - off] : 0;
        __syncthreads();
        lds[t] += v;
        __syncthreads();
    }
    int excl = t ? lds[t - 1] : 0;
    if (t == 255) bsum[blockIdx.x] = lds[255];
    if (i0 + 0 < N) base[i0 + 0] = excl;
    if (i0 + 1 < N) base[i0 + 1] = excl + d0;
    if (i0 + 2 < N) base[i0 + 2] = excl + d0 + d1;
    if (i0 + 3 < N) base[i0 + 3] = excl + d0 + d1 + d2;
}

__global__ __launch_bounds__(256) void scan_b(int* __restrict__ bsum, int nb) {
    __shared__ int lds[1024];
    int t = threadIdx.x;
    for (int i = t; i < nb; i += 256) lds[i] = bsum[i];
    __syncthreads();
    if (t == 0) {
        int run = 0;
        for (int i = 0; i < nb; i++) { int v = lds[i]; lds[i] = run; run += v; }
    }
    __syncthreads();
    for (int i = t; i < nb; i += 256) bsum[i] = lds[i];
}

// finalize base; thread owning i with i%64==0 also seeds its bucket cursor
__global__ __launch_bounds__(256) void scan_c(int* __restrict__ base,
                                              const int* __restrict__ bsum,
                                              int* __restrict__ bcur, int N, int E) {
    int i = blockIdx.x * 256 + threadIdx.x;
    if (i < N) {
        int v = base[i] + bsum[i >> 10];
        base[i] = v;
        if ((i & 63) == 0) bcur[i >> 6] = v;   // bucket cursor = segment start
    } else if (i == N) base[N] = E;
}

// ---------------- K4a: edge value + bucket-append (write-local scatter) ----------------
__global__ __launch_bounds__(256) void k4_scatter(
    const int* __restrict__ src, const int* __restrict__ dst,
    const float* __restrict__ noise, const float4* __restrict__ pp,
    int* __restrict__ bcur, float2* __restrict__ ed, int E)
{
    int e = blockIdx.x * 256 + threadIdx.x;
    if (e >= E) return;
    int s = src[e], d = dst[e];
    float4 ps = pp[s], pd = pp[d];
    float loc = ps.x + pd.y;
    loc = loc >= 0.f ? loc : NSLOPE * loc;
    float ev = loc + __expf(ps.z + pd.w) * noise[e];
    int pos = atomicAdd(&bcur[d >> 6], 1);   // ~1563 hot cursors, tails stay in L2
    float2 v; v.x = ev;
    v.y = __uint_as_float((unsigned)s | ((unsigned)(d & 63) << 26));
    ed[pos] = v;
}

// ---------------- K4b: per-bucket LDS counting sort -> dst-sorted CSR (coalesced) ----------------
__global__ __launch_bounds__(256) void k4_sort(
    const int* __restrict__ base, const float2* __restrict__ ed,
    float2* __restrict__ ed2, int N)
{
    __shared__ float    s_ev[CAP];
    __shared__ unsigned s_pk[CAP];
    __shared__ float    o_ev[CAP];
    __shared__ unsigned o_sr[CAP];
    __shared__ int c[64], ox[64], c2[64];
    int t = threadIdx.x;
    int n0 = blockIdx.x << 6;
    int n1 = n0 + 64; if (n1 > N) n1 = N;
    int gb = base[n0], cnt = base[n1] - gb;
    if (t < 64) { c[t] = 0; c2[t] = 0; }
    __syncthreads();
    if (cnt <= CAP) {
        for (int i = t; i < cnt; i += 256) {
            float2 v = ed[gb + i];
            unsigned pk = __float_as_uint(v.y);
            s_ev[i] = v.x; s_pk[i] = pk;
            atomicAdd(&c[pk >> 26], 1);
        }
        __syncthreads();
        if (t < 64) {
            int val = c[t], inc = val;
            #pragma unroll
            for (int off = 1; off < 64; off <<= 1) {
                int u = __shfl_up(inc, off);
                if (t >= off) inc += u;
            }
            ox[t] = inc - val;   // exclusive in-bucket offset == global CSR offset - gb
        }
        __syncthreads();
        for (int i = t; i < cnt; i += 256) {
            unsigned pk = s_pk[i];
            int dl = pk >> 26;
            int p = ox[dl] + atomicAdd(&c2[dl], 1);
            o_ev[p] = s_ev[i];
            o_sr[p] = pk & 0x03FFFFFFu;
        }
        __syncthreads();
        for (int i = t; i < cnt; i += 256) {
            float2 v; v.x = o_ev[i]; v.y = __uint_as_float(o_sr[i]);
            ed2[gb + i] = v;
        }
    } else {
        // fallback (never for this input): global counting-sort scatter
        for (int i = t; i < cnt; i += 256)
            atomicAdd(&c[__float_as_uint(ed[gb + i].y) >> 26], 1);
        __syncthreads();
        if (t < 64) {
            int val = c[t], inc = val;
            #pragma unroll
            for (int off = 1; off < 64; off <<= 1) {
                int u = __shfl_up(inc, off);
                if (t >= off) inc += u;
            }
            ox[t] = inc - val;
        }
        __syncthreads();
        for (int i = t; i < cnt; i += 256) {
            float2 v = ed[gb + i];
            unsigned pk = __float_as_uint(v.y);
            int dl = pk >> 26;
            int p = ox[dl] + atomicAdd(&c2[dl], 1);
            float2 o; o.x = v.x; o.y = __uint_as_float(pk & 0x03FFFFFFu);
            ed2[gb + p] = o;
        }
    }
}

// ---------------- K5: one wave per node, online softmax, 4 edges in flight ----------------
__global__ __launch_bounds__(256) void k5_node(
    const int* __restrict__ base, const float2* __restrict__ ed2,
    const float* __restrict__ h, const float* __restrict__ bias,
    float* __restrict__ out, int N)
{
    int wid = (int)((blockIdx.x * 256 + threadIdx.x) >> 6);
    int lane = threadIdx.x & 63;
    if (wid >= N) return;
    int b0 = base[wid], b1 = base[wid + 1];
    float bl = bias[lane];
    long ob = (long)wid * 64 + lane;
    if (b1 == b0) { out[ob] = bl; return; }
    float m = -INFINITY, acc = 0.f, ssum = 0.f;
    int j = b0;
    for (; j + 4 <= b1; j += 4) {
        float2 e0 = nt_load_f2(&ed2[j]),     e1 = nt_load_f2(&ed2[j + 1]),
               e2 = nt_load_f2(&ed2[j + 2]), e3 = nt_load_f2(&ed2[j + 3]);
        float v0 = h[(long)__float_as_int(e0.y) * 64 + lane];
        float v1 = h[(long)__float_as_int(e1.y) * 64 + lane];
        float v2 = h[(long)__float_as_int(e2.y) * 64 + lane];
        float v3 = h[(long)__float_as_int(e3.y) * 64 + lane];
        float mx = fmaxf(fmaxf(fmaxf(e0.x, e1.x), fmaxf(e2.x, e3.x)), m);
        float alpha = __expf(m - mx);
        float w0 = __expf(e0.x - mx), w1 = __expf(e1.x - mx),
              w2 = __expf(e2.x - mx), w3 = __expf(e3.x - mx);
        ssum = ssum * alpha + ((w0 + w1) + (w2 + w3));
        acc  = acc  * alpha + (w0 * v0 + w1 * v1) + (w2 * v2 + w3 * v3);
        m = mx;
    }
    for (; j < b1; j++) {
        float2 e = nt_load_f2(&ed2[j]);
        float v = h[(long)__float_as_int(e.y) * 64 + lane];
        float mx = fmaxf(m, e.x);
        float alpha = __expf(m - mx);
        float w = __expf(e.x - mx);
        ssum = ssum * alpha + w;
        acc  = acc  * alpha + w * v;
        m = mx;
    }
    out[ob] = acc / ssum + bl;
}

extern "C" void kernel_launch(void* const* d_in, const int* in_sizes, int n_in,
                              void* d_out, int out_size, void* d_ws, size_t ws_size,
                              hipStream_t stream) {
    const float* feat  = (const float*)d_in[0];
    const float* wfc   = (const float*)d_in[1];
    const float* wpost = (const float*)d_in[2];
    const float* bpost = (const float*)d_in[3];
    const float* bias  = (const float*)d_in[4];
    const float* noise = (const float*)d_in[5];
    const int*   src   = (const int*)d_in[6];
    const int*   dst   = (const int*)d_in[7];
    int N = in_sizes[0] / 128;
    int E = in_sizes[6];
    float* out = (float*)d_out;
    int NB = (N + 63) / 64;        // buckets of 64 dst nodes

    // ws layout (4B units): ed[2E] | ed2[2E] | h[N*64] | pp[N*4] | deg[N] |
    //                       base[N+1] | bsum[1024] | bcur[NB]
    float*  ws   = (float*)d_ws;
    float2* ed   = (float2*)ws;
    float2* ed2  = (float2*)(ws + (size_t)2 * E);
    float*  h    = ws + (size_t)4 * E;
    float4* pp   = (float4*)(h + (size_t)N * 64);
    int*    deg  = (int*)(h + (size_t)N * 64 + (size_t)N * 4);
    int*    base = deg + N;
    int*    bsum = base + (N + 1);
    int*    bcur = bsum + 1024;

    int nb = (N + 1023) / 1024;

    hipLaunchKernelGGL(k0_zero, dim3((N + 255) / 256), dim3(256), 0, stream, deg, N);
    hipLaunchKernelGGL(k1_proj, dim3((N + 15) / 16), dim3(256), 0, stream,
                       feat, wfc, wpost, bpost, h, pp, N);
    hipLaunchKernelGGL(k2_hist, dim3((E + 255) / 256), dim3(256), 0, stream, dst, deg, E);
    hipLaunchKernelGGL(scan_a, dim3(nb), dim3(256), 0, stream, deg, base, bsum, N);
    hipLaunchKernelGGL(scan_b, dim3(1), dim3(256), 0, stream, bsum, nb);
    hipLaunchKernelGGL(scan_c, dim3((N + 256) / 256), dim3(256), 0, stream,
                       base, bsum, bcur, N, E);
    hipLaunchKernelGGL(k4_scatter, dim3((E + 255) / 256), dim3(256), 0, stream,
                       src, dst, noise, pp, bcur, ed, E);
    hipLaunchKernelGGL(k4_sort, dim3(NB), dim3(256), 0, stream, base, ed, ed2, N);
    long k5_threads = (long)N * 64;
    hipLaunchKernelGGL(k5_node, dim3((unsigned)((k5_threads + 255) / 256)), dim3(256), 0, stream,
                       base, ed2, h, bias, out, N);
}

// Round 6
// 435.697 us; speedup vs baseline: 1.3501x; 1.3501x over previous
//
#include <hip/hip_runtime.h>
#include <math.h>

#define NSLOPE 0.2f
#define CAP 4096          // max edges per 64-node bucket handled in LDS
#define CSTRIDE 16        // bucket-cursor stride in ints (64B: one line per cursor)

__device__ __forceinline__ float2 nt_load_f2(const float2* p) {
    union { unsigned long long u; float2 f; } c;
    c.u = __builtin_nontemporal_load((const unsigned long long*)p);
    return c.f;
}

// ---------------- K0: zero degree counters ----------------
__global__ __launch_bounds__(256) void k0_zero(int* __restrict__ deg, int n) {
    int i = blockIdx.x * 256 + threadIdx.x;
    if (i < n) deg[i] = 0;
}

// ---------------- K1: h = feat @ W_fc, fused pp = h @ W_post + b_post ----------------
__global__ __launch_bounds__(256) void k1_proj(
    const float* __restrict__ feat, const float* __restrict__ wfc,
    const float* __restrict__ wpost, const float* __restrict__ bpost,
    float* __restrict__ h, float4* __restrict__ pp, int n)
{
    __shared__ float wfc_s[128 * 64];   // 32 KB
    __shared__ float feat_s[16 * 128];  // 8 KB
    int t = threadIdx.x;
    for (int i = t; i < 128 * 64 / 4; i += 256)
        ((float4*)wfc_s)[i] = ((const float4*)wfc)[i];
    int row0 = blockIdx.x * 16;
    {
        const float4* fv = (const float4*)(feat + (long)row0 * 128);
        int lim = (n - row0) * (128 / 4);
        if (lim > 16 * 128 / 4) lim = 16 * 128 / 4;
        for (int i = t; i < lim; i += 256)
            ((float4*)feat_s)[i] = fv[i];
    }
    __syncthreads();
    int lane = t & 63, wv = t >> 6;
    const float* fr = feat_s + wv * 4 * 128;
    float acc[4] = {0.f, 0.f, 0.f, 0.f};
    #pragma unroll 2
    for (int k = 0; k < 128; k += 4) {
        float w0 = wfc_s[(k + 0) * 64 + lane];
        float w1 = wfc_s[(k + 1) * 64 + lane];
        float w2 = wfc_s[(k + 2) * 64 + lane];
        float w3 = wfc_s[(k + 3) * 64 + lane];
        #pragma unroll
        for (int r = 0; r < 4; r++) {
            float4 f = *(const float4*)(fr + r * 128 + k);  // b128 broadcast
            acc[r] += f.x * w0 + f.y * w1 + f.z * w2 + f.w * w3;
        }
    }
    int r0 = row0 + wv * 4;
    #pragma unroll
    for (int r = 0; r < 4; r++)
        if (r0 + r < n) h[(long)(r0 + r) * 64 + lane] = acc[r];
    float4 wp = ((const float4*)wpost)[lane];
    float4 bp = *((const float4*)bpost);
    #pragma unroll
    for (int r = 0; r < 4; r++) {
        float cx = acc[r] * wp.x, cy = acc[r] * wp.y,
              cz = acc[r] * wp.z, cw = acc[r] * wp.w;
        #pragma unroll
        for (int off = 32; off > 0; off >>= 1) {
            cx += __shfl_down(cx, off);
            cy += __shfl_down(cy, off);
            cz += __shfl_down(cz, off);
            cw += __shfl_down(cw, off);
        }
        if (lane == 0 && r0 + r < n) {
            float4 o;
            o.x = cx + bp.x; o.y = cy + bp.y; o.z = cz + bp.z; o.w = cw + bp.w;
            pp[r0 + r] = o;
        }
    }
}

// ---------------- K2: degree histogram over dst ----------------
__global__ __launch_bounds__(256) void k2_hist(const int* __restrict__ dst,
                                               int* __restrict__ deg, int E) {
    int e = blockIdx.x * 256 + threadIdx.x;
    if (e < E) atomicAdd(&deg[dst[e]], 1);
}

// ---------------- scan: exclusive prefix of deg -> base ----------------
__global__ __launch_bounds__(256) void scan_a(const int* __restrict__ deg,
                                              int* __restrict__ base,
                                              int* __restrict__ bsum, int N) {
    __shared__ int lds[256];
    int t = threadIdx.x;
    int i0 = blockIdx.x * 1024 + t * 4;
    int d0 = (i0 + 0 < N) ? deg[i0 + 0] : 0;
    int d1 = (i0 + 1 < N) ? deg[i0 + 1] : 0;
    int d2 = (i0 + 2 < N) ? deg[i0 + 2] : 0;
    int d3 = (i0 + 3 < N) ? deg[i0 + 3] : 0;
    lds[t] = d0 + d1 + d2 + d3;
    __syncthreads();
    for (int off = 1; off < 256; off <<= 1) {
        int v = (t >= off) ? lds[t - off] : 0;
        __syncthreads();
        lds[t] += v;
        __syncthreads();
    }
    int excl = t ? lds[t - 1] : 0;
    if (t == 255) bsum[blockIdx.x] = lds[255];
    if (i0 + 0 < N) base[i0 + 0] = excl;
    if (i0 + 1 < N) base[i0 + 1] = excl + d0;
    if (i0 + 2 < N) base[i0 + 2] = excl + d0 + d1;
    if (i0 + 3 < N) base[i0 + 3] = excl + d0 + d1 + d2;
}

__global__ __launch_bounds__(256) void scan_b(int* __restrict__ bsum, int nb) {
    __shared__ int lds[1024];
    int t = threadIdx.x;
    for (int i = t; i < nb; i += 256) lds[i] = bsum[i];
    __syncthreads();
    if (t == 0) {
        int run = 0;
        for (int i = 0; i < nb; i++) { int v = lds[i]; lds[i] = run; run += v; }
    }
    __syncthreads();
    for (int i = t; i < nb; i += 256) bsum[i] = lds[i];
}

// finalize base; node i%64==0 seeds its bucket cursor (64B-strided)
__global__ __launch_bounds__(256) void scan_c(int* __restrict__ base,
                                              const int* __restrict__ bsum,
                                              int* __restrict__ bcur, int N, int E) {
    int i = blockIdx.x * 256 + threadIdx.x;
    if (i < N) {
        int v = base[i] + bsum[i >> 10];
        base[i] = v;
        if ((i & 63) == 0) bcur[(i >> 6) * CSTRIDE] = v;  // one cursor per cache line
    } else if (i == N) base[N] = E;
}

// ---------------- K4a: edge value + bucket-append (write-local scatter) ----------------
__global__ __launch_bounds__(256) void k4_scatter(
    const int* __restrict__ src, const int* __restrict__ dst,
    const float* __restrict__ noise, const float4* __restrict__ pp,
    int* __restrict__ bcur, float2* __restrict__ ed, int E)
{
    int e = blockIdx.x * 256 + threadIdx.x;
    if (e >= E) return;
    int s = src[e], d = dst[e];
    float4 ps = pp[s], pd = pp[d];
    float loc = ps.x + pd.y;
    loc = loc >= 0.f ? loc : NSLOPE * loc;
    float ev = loc + __expf(ps.z + pd.w) * noise[e];
    int pos = atomicAdd(&bcur[(d >> 6) * CSTRIDE], 1);  // padded: no line sharing
    float2 v; v.x = ev;
    v.y = __uint_as_float((unsigned)s | ((unsigned)(d & 63) << 26));
    ed[pos] = v;                       // cached store: L2 write-combines tail lines
}

// ---------------- K4b: per-bucket LDS counting sort -> dst-sorted CSR (coalesced) ----------------
__global__ __launch_bounds__(256) void k4_sort(
    const int* __restrict__ base, const float2* __restrict__ ed,
    float2* __restrict__ ed2, int N)
{
    __shared__ float    s_ev[CAP];
    __shared__ unsigned s_pk[CAP];
    __shared__ float    o_ev[CAP];
    __shared__ unsigned o_sr[CAP];
    __shared__ int c[64], ox[64], c2[64];
    int t = threadIdx.x;
    int n0 = blockIdx.x << 6;
    int n1 = n0 + 64; if (n1 > N) n1 = N;
    int gb = base[n0], cnt = base[n1] - gb;
    if (t < 64) { c[t] = 0; c2[t] = 0; }
    __syncthreads();
    if (cnt <= CAP) {
        for (int i = t; i < cnt; i += 256) {
            float2 v = ed[gb + i];
            unsigned pk = __float_as_uint(v.y);
            s_ev[i] = v.x; s_pk[i] = pk;
            atomicAdd(&c[pk >> 26], 1);
        }
        __syncthreads();
        if (t < 64) {
            int val = c[t], inc = val;
            #pragma unroll
            for (int off = 1; off < 64; off <<= 1) {
                int u = __shfl_up(inc, off);
                if (t >= off) inc += u;
            }
            ox[t] = inc - val;
        }
        __syncthreads();
        for (int i = t; i < cnt; i += 256) {
            unsigned pk = s_pk[i];
            int dl = pk >> 26;
            int p = ox[dl] + atomicAdd(&c2[dl], 1);
            o_ev[p] = s_ev[i];
            o_sr[p] = pk & 0x03FFFFFFu;
        }
        __syncthreads();
        for (int i = t; i < cnt; i += 256) {
            float2 v; v.x = o_ev[i]; v.y = __uint_as_float(o_sr[i]);
            ed2[gb + i] = v;
        }
    } else {
        // fallback (never for this input): global counting-sort scatter
        for (int i = t; i < cnt; i += 256)
            atomicAdd(&c[__float_as_uint(ed[gb + i].y) >> 26], 1);
        __syncthreads();
        if (t < 64) {
            int val = c[t], inc = val;
            #pragma unroll
            for (int off = 1; off < 64; off <<= 1) {
                int u = __shfl_up(inc, off);
                if (t >= off) inc += u;
            }
            ox[t] = inc - val;
        }
        __syncthreads();
        for (int i = t; i < cnt; i += 256) {
            float2 v = ed[gb + i];
            unsigned pk = __float_as_uint(v.y);
            int dl = pk >> 26;
            int p = ox[dl] + atomicAdd(&c2[dl], 1);
            float2 o; o.x = v.x; o.y = __uint_as_float(pk & 0x03FFFFFFu);
            ed2[gb + p] = o;
        }
    }
}

// ---------------- K5: one wave per node, online softmax, 4 edges in flight ----------------
__global__ __launch_bounds__(256) void k5_node(
    const int* __restrict__ base, const float2* __restrict__ ed2,
    const float* __restrict__ h, const float* __restrict__ bias,
    float* __restrict__ out, int N)
{
    int wid = (int)((blockIdx.x * 256 + threadIdx.x) >> 6);
    int lane = threadIdx.x & 63;
    if (wid >= N) return;
    int b0 = base[wid], b1 = base[wid + 1];
    float bl = bias[lane];
    long ob = (long)wid * 64 + lane;
    if (b1 == b0) { out[ob] = bl; return; }
    float m = -INFINITY, acc = 0.f, ssum = 0.f;
    int j = b0;
    for (; j + 4 <= b1; j += 4) {
        float2 e0 = nt_load_f2(&ed2[j]),     e1 = nt_load_f2(&ed2[j + 1]),
               e2 = nt_load_f2(&ed2[j + 2]), e3 = nt_load_f2(&ed2[j + 3]);
        float v0 = h[(long)__float_as_int(e0.y) * 64 + lane];
        float v1 = h[(long)__float_as_int(e1.y) * 64 + lane];
        float v2 = h[(long)__float_as_int(e2.y) * 64 + lane];
        float v3 = h[(long)__float_as_int(e3.y) * 64 + lane];
        float mx = fmaxf(fmaxf(fmaxf(e0.x, e1.x), fmaxf(e2.x, e3.x)), m);
        float alpha = __expf(m - mx);
        float w0 = __expf(e0.x - mx), w1 = __expf(e1.x - mx),
              w2 = __expf(e2.x - mx), w3 = __expf(e3.x - mx);
        ssum = ssum * alpha + ((w0 + w1) + (w2 + w3));
        acc  = acc  * alpha + (w0 * v0 + w1 * v1) + (w2 * v2 + w3 * v3);
        m = mx;
    }
    for (; j < b1; j++) {
        float2 e = nt_load_f2(&ed2[j]);
        float v = h[(long)__float_as_int(e.y) * 64 + lane];
        float mx = fmaxf(m, e.x);
        float alpha = __expf(m - mx);
        float w = __expf(e.x - mx);
        ssum = ssum * alpha + w;
        acc  = acc  * alpha + w * v;
        m = mx;
    }
    out[ob] = acc / ssum + bl;
}

extern "C" void kernel_launch(void* const* d_in, const int* in_sizes, int n_in,
                              void* d_out, int out_size, void* d_ws, size_t ws_size,
                              hipStream_t stream) {
    const float* feat  = (const float*)d_in[0];
    const float* wfc   = (const float*)d_in[1];
    const float* wpost = (const float*)d_in[2];
    const float* bpost = (const float*)d_in[3];
    const float* bias  = (const float*)d_in[4];
    const float* noise = (const float*)d_in[5];
    const int*   src   = (const int*)d_in[6];
    const int*   dst   = (const int*)d_in[7];
    int N = in_sizes[0] / 128;
    int E = in_sizes[6];
    float* out = (float*)d_out;
    int NB = (N + 63) / 64;        // buckets of 64 dst nodes

    // ws layout (4B units): ed[2E] | ed2[2E] | h[N*64] | pp[N*4] | deg[N] |
    //                       base[N+1] | bsum[1024] | bcur[NB*CSTRIDE]
    float*  ws   = (float*)d_ws;
    float2* ed   = (float2*)ws;
    float2* ed2  = (float2*)(ws + (size_t)2 * E);
    float*  h    = ws + (size_t)4 * E;
    float4* pp   = (float4*)(h + (size_t)N * 64);
    int*    deg  = (int*)(h + (size_t)N * 64 + (size_t)N * 4);
    int*    base = deg + N;
    int*    bsum = base + (N + 1);
    int*    bcur = bsum + 1024;

    int nb = (N + 1023) / 1024;

    hipLaunchKernelGGL(k0_zero, dim3((N + 255) / 256), dim3(256), 0, stream, deg, N);
    hipLaunchKernelGGL(k1_proj, dim3((N + 15) / 16), dim3(256), 0, stream,
                       feat, wfc, wpost, bpost, h, pp, N);
    hipLaunchKernelGGL(k2_hist, dim3((E + 255) / 256), dim3(256), 0, stream, dst, deg, E);
    hipLaunchKernelGGL(scan_a, dim3(nb), dim3(256), 0, stream, deg, base, bsum, N);
    hipLaunchKernelGGL(scan_b, dim3(1), dim3(256), 0, stream, bsum, nb);
    hipLaunchKernelGGL(scan_c, dim3((N + 256) / 256), dim3(256), 0, stream,
                       base, bsum, bcur, N, E);
    hipLaunchKernelGGL(k4_scatter, dim3((E + 255) / 256), dim3(256), 0, stream,
                       src, dst, noise, pp, bcur, ed, E);
    hipLaunchKernelGGL(k4_sort, dim3(NB), dim3(256), 0, stream, base, ed, ed2, N);
    long k5_threads = (long)N * 64;
    hipLaunchKernelGGL(k5_node, dim3((unsigned)((k5_threads + 255) / 256)), dim3(256), 0, stream,
                       base, ed2, h, bias, out, N);
}

// Round 7
// 434.053 us; speedup vs baseline: 1.3552x; 1.0038x over previous
//
#include <hip/hip_runtime.h>
#include <math.h>

#define NSLOPE 0.2f
#define CAP 4096          // max edges per 64-node bucket handled in LDS
#define CSTRIDE 16        // bucket-counter stride in ints (64B: one line per counter)

// ---------------- Z0: zero per-bucket counters ----------------
__global__ __launch_bounds__(256) void z0_zero(int* __restrict__ bcnt, int NB) {
    int i = blockIdx.x * 256 + threadIdx.x;
    if (i < NB) bcnt[i * CSTRIDE] = 0;
}

// ---------------- K1: h = feat @ W_fc, fused pp = h @ W_post + b_post ----------------
__global__ __launch_bounds__(256) void k1_proj(
    const float* __restrict__ feat, const float* __restrict__ wfc,
    const float* __restrict__ wpost, const float* __restrict__ bpost,
    float* __restrict__ h, float4* __restrict__ pp, int n)
{
    __shared__ float wfc_s[128 * 64];   // 32 KB
    __shared__ float feat_s[16 * 128];  // 8 KB
    int t = threadIdx.x;
    for (int i = t; i < 128 * 64 / 4; i += 256)
        ((float4*)wfc_s)[i] = ((const float4*)wfc)[i];
    int row0 = blockIdx.x * 16;
    {
        const float4* fv = (const float4*)(feat + (long)row0 * 128);
        int lim = (n - row0) * (128 / 4);
        if (lim > 16 * 128 / 4) lim = 16 * 128 / 4;
        for (int i = t; i < lim; i += 256)
            ((float4*)feat_s)[i] = fv[i];
    }
    __syncthreads();
    int lane = t & 63, wv = t >> 6;
    const float* fr = feat_s + wv * 4 * 128;
    float acc[4] = {0.f, 0.f, 0.f, 0.f};
    #pragma unroll 2
    for (int k = 0; k < 128; k += 4) {
        float w0 = wfc_s[(k + 0) * 64 + lane];
        float w1 = wfc_s[(k + 1) * 64 + lane];
        float w2 = wfc_s[(k + 2) * 64 + lane];
        float w3 = wfc_s[(k + 3) * 64 + lane];
        #pragma unroll
        for (int r = 0; r < 4; r++) {
            float4 f = *(const float4*)(fr + r * 128 + k);  // b128 broadcast
            acc[r] += f.x * w0 + f.y * w1 + f.z * w2 + f.w * w3;
        }
    }
    int r0 = row0 + wv * 4;
    #pragma unroll
    for (int r = 0; r < 4; r++)
        if (r0 + r < n) h[(long)(r0 + r) * 64 + lane] = acc[r];
    float4 wp = ((const float4*)wpost)[lane];
    float4 bp = *((const float4*)bpost);
    #pragma unroll
    for (int r = 0; r < 4; r++) {
        float cx = acc[r] * wp.x, cy = acc[r] * wp.y,
              cz = acc[r] * wp.z, cw = acc[r] * wp.w;
        #pragma unroll
        for (int off = 32; off > 0; off >>= 1) {
            cx += __shfl_down(cx, off);
            cy += __shfl_down(cy, off);
            cz += __shfl_down(cz, off);
            cw += __shfl_down(cw, off);
        }
        if (lane == 0 && r0 + r < n) {
            float4 o;
            o.x = cx + bp.x; o.y = cy + bp.y; o.z = cz + bp.z; o.w = cw + bp.w;
            pp[r0 + r] = o;
        }
    }
}

// ---------------- K2: per-BUCKET histogram (padded counters, no line sharing) ----------------
__global__ __launch_bounds__(256) void k2_bhist(const int* __restrict__ dst,
                                                int* __restrict__ bcnt, int E) {
    int e = blockIdx.x * 256 + threadIdx.x;
    if (e < E) atomicAdd(&bcnt[(dst[e] >> 6) * CSTRIDE], 1);
}

// ---------------- BSCAN: single-block exclusive scan over NB buckets ----------------
__global__ __launch_bounds__(256) void bscan(const int* __restrict__ bcnt,
                                             int* __restrict__ bbase,
                                             int* __restrict__ bcur,
                                             int* __restrict__ base,
                                             int NB, int N) {
    __shared__ int lds[256];
    int t = threadIdx.x;
    int per = (NB + 255) >> 8;
    int s0 = t * per;
    int sum = 0;
    for (int k = 0; k < per; k++) {
        int b = s0 + k;
        if (b < NB) sum += bcnt[b * CSTRIDE];
    }
    lds[t] = sum;
    __syncthreads();
    for (int off = 1; off < 256; off <<= 1) {
        int v = (t >= off) ? lds[t - off] : 0;
        __syncthreads();
        lds[t] += v;
        __syncthreads();
    }
    int run = t ? lds[t - 1] : 0;
    for (int k = 0; k < per; k++) {
        int b = s0 + k;
        if (b < NB) {
            bbase[b] = run;
            bcur[b * CSTRIDE] = run;
            run += bcnt[b * CSTRIDE];
        }
    }
    if (t == 255) { bbase[NB] = lds[255]; base[N] = lds[255]; }
}

// ---------------- K4a: edge value + bucket-append (write-local scatter) ----------------
__global__ __launch_bounds__(256) void k4_scatter(
    const int* __restrict__ src, const int* __restrict__ dst,
    const float* __restrict__ noise, const float4* __restrict__ pp,
    int* __restrict__ bcur, float2* __restrict__ ed, int E)
{
    int e = blockIdx.x * 256 + threadIdx.x;
    if (e >= E) return;
    int s = src[e], d = dst[e];
    float4 ps = pp[s], pd = pp[d];
    float loc = ps.x + pd.y;
    loc = loc >= 0.f ? loc : NSLOPE * loc;
    float ev = loc + __expf(ps.z + pd.w) * noise[e];
    int pos = atomicAdd(&bcur[(d >> 6) * CSTRIDE], 1);
    float2 v; v.x = ev;
    v.y = __uint_as_float((unsigned)s | ((unsigned)(d & 63) << 26));
    ed[pos] = v;
}

// ---------------- K4b: per-bucket LDS counting sort + softmax-normalize + base write ----------------
__global__ __launch_bounds__(256) void k4_sort(
    const int* __restrict__ bbase, const float2* __restrict__ ed,
    float2* __restrict__ ed2, int* __restrict__ base, int N)
{
    __shared__ float    s_ev[CAP];
    __shared__ unsigned s_pk[CAP];
    __shared__ float    o_ev[CAP];
    __shared__ unsigned o_sr[CAP];
    __shared__ int c[64], ox[64], c2[64];
    int t = threadIdx.x;
    int b = blockIdx.x;
    int n0 = b << 6;
    int nn = N - n0; if (nn > 64) nn = 64;
    int gb = bbase[b], cnt = bbase[b + 1] - gb;
    if (t < 64) { c[t] = 0; c2[t] = 0; }
    __syncthreads();
    if (cnt <= CAP) {
        for (int i = t; i < cnt; i += 256) {
            float2 v = ed[gb + i];
            unsigned pk = __float_as_uint(v.y);
            s_ev[i] = v.x; s_pk[i] = pk;
            atomicAdd(&c[pk >> 26], 1);
        }
        __syncthreads();
        if (t < 64) {
            int val = c[t], inc = val;
            #pragma unroll
            for (int off = 1; off < 64; off <<= 1) {
                int u = __shfl_up(inc, off);
                if (t >= off) inc += u;
            }
            ox[t] = inc - val;
            if (t < nn) base[n0 + t] = gb + inc - val;   // per-node CSR base
        }
        __syncthreads();
        for (int i = t; i < cnt; i += 256) {
            unsigned pk = s_pk[i];
            int dl = pk >> 26;
            int p = ox[dl] + atomicAdd(&c2[dl], 1);
            o_ev[p] = s_ev[i];
            o_sr[p] = pk & 0x03FFFFFFu;
        }
        __syncthreads();
        // per-node softmax weights, normalized in LDS (t<64 owns node t)
        if (t < 64 && t < nn) {
            int i0 = ox[t], i1 = i0 + c[t];
            float m = -INFINITY;
            for (int i = i0; i < i1; i++) m = fmaxf(m, o_ev[i]);
            float ssum = 0.f;
            for (int i = i0; i < i1; i++) { float w = __expf(o_ev[i] - m); o_ev[i] = w; ssum += w; }
            float inv = 1.f / ssum;
            for (int i = i0; i < i1; i++) o_ev[i] *= inv;
        }
        __syncthreads();
        for (int i = t; i < cnt; i += 256) {
            float2 v; v.x = o_ev[i]; v.y = __uint_as_float(o_sr[i]);
            ed2[gb + i] = v;
        }
    } else {
        // fallback for oversized buckets (never for this input): global counting sort
        for (int i = t; i < cnt; i += 256)
            atomicAdd(&c[__float_as_uint(ed[gb + i].y) >> 26], 1);
        __syncthreads();
        if (t < 64) {
            int val = c[t], inc = val;
            #pragma unroll
            for (int off = 1; off < 64; off <<= 1) {
                int u = __shfl_up(inc, off);
                if (t >= off) inc += u;
            }
            ox[t] = inc - val;
            if (t < nn) base[n0 + t] = gb + inc - val;
        }
        __syncthreads();
        for (int i = t; i < cnt; i += 256) {
            float2 v = ed[gb + i];
            unsigned pk = __float_as_uint(v.y);
            int dl = pk >> 26;
            int p = ox[dl] + atomicAdd(&c2[dl], 1);
            float2 o; o.x = v.x; o.y = __uint_as_float(pk & 0x03FFFFFFu);
            ed2[gb + p] = o;
        }
        __syncthreads();
        __threadfence();
        if (t < 64 && t < nn) {
            int i0 = gb + ox[t], i1 = i0 + c[t];
            float m = -INFINITY;
            for (int i = i0; i < i1; i++) m = fmaxf(m, ed2[i].x);
            float ssum = 0.f;
            for (int i = i0; i < i1; i++) ssum += __expf(ed2[i].x - m);
            float inv = 1.f / ssum;
            for (int i = i0; i < i1; i++) {
                float2 v = ed2[i];
                v.x = __expf(v.x - m) * inv;
                ed2[i] = v;
            }
        }
    }
}

// ---------------- K5: pure normalized-weighted gather-sum ----------------
// wave = node; sub = lane>>4 (edge slot 0..3), c = lane&15 (float4 feature group)
__global__ __launch_bounds__(256) void k5_node(
    const int* __restrict__ base, const float2* __restrict__ ed2,
    const float4* __restrict__ h4, const float4* __restrict__ bias4,
    float4* __restrict__ out4, int N)
{
    int wid = (int)((blockIdx.x * 256 + threadIdx.x) >> 6);
    int lane = threadIdx.x & 63;
    if (wid >= N) return;
    int c = lane & 15, sub = lane >> 4;
    int b0 = base[wid], b1 = base[wid + 1];
    float4 a0 = {0.f, 0.f, 0.f, 0.f}, a1 = {0.f, 0.f, 0.f, 0.f};
    int jb = b0;
    for (; jb + 8 <= b1; jb += 8) {          // 8 edges in flight, fully in-range
        float2 e0 = ed2[jb + sub];
        float2 e1 = ed2[jb + 4 + sub];
        float4 v0 = h4[(long)__float_as_int(e0.y) * 16 + c];
        float4 v1 = h4[(long)__float_as_int(e1.y) * 16 + c];
        a0.x += e0.x * v0.x; a0.y += e0.x * v0.y; a0.z += e0.x * v0.z; a0.w += e0.x * v0.w;
        a1.x += e1.x * v1.x; a1.y += e1.x * v1.y; a1.z += e1.x * v1.z; a1.w += e1.x * v1.w;
    }
    for (; jb < b1; jb += 4) {               // masked tail
        int jj = jb + sub;
        float w = 0.f; int s = 0;
        if (jj < b1) { float2 e = ed2[jj]; w = e.x; s = __float_as_int(e.y); }
        float4 v = h4[(long)s * 16 + c];     // s=0 row: hot in cache, w=0 neutralizes
        a0.x += w * v.x; a0.y += w * v.y; a0.z += w * v.z; a0.w += w * v.w;
    }
    a0.x += a1.x; a0.y += a1.y; a0.z += a1.z; a0.w += a1.w;
    // reduce across the 4 sub-slots (lane bits 4,5)
    a0.x += __shfl_xor(a0.x, 16); a0.y += __shfl_xor(a0.y, 16);
    a0.z += __shfl_xor(a0.z, 16); a0.w += __shfl_xor(a0.w, 16);
    a0.x += __shfl_xor(a0.x, 32); a0.y += __shfl_xor(a0.y, 32);
    a0.z += __shfl_xor(a0.z, 32); a0.w += __shfl_xor(a0.w, 32);
    if (sub == 0) {
        float4 bp = bias4[c];
        float4 o;
        o.x = a0.x + bp.x; o.y = a0.y + bp.y; o.z = a0.z + bp.z; o.w = a0.w + bp.w;
        out4[(long)wid * 16 + c] = o;
    }
}

extern "C" void kernel_launch(void* const* d_in, const int* in_sizes, int n_in,
                              void* d_out, int out_size, void* d_ws, size_t ws_size,
                              hipStream_t stream) {
    const float* feat  = (const float*)d_in[0];
    const float* wfc   = (const float*)d_in[1];
    const float* wpost = (const float*)d_in[2];
    const float* bpost = (const float*)d_in[3];
    const float* bias  = (const float*)d_in[4];
    const float* noise = (const float*)d_in[5];
    const int*   src   = (const int*)d_in[6];
    const int*   dst   = (const int*)d_in[7];
    int N = in_sizes[0] / 128;
    int E = in_sizes[6];
    int NB = (N + 63) / 64;

    // ws (4B units): ed[2E] | ed2[2E] | h[N*64] | pp[N*4] | base[N+1] |
    //                bbase[NB+1] | bcnt[NB*CSTRIDE] | bcur[NB*CSTRIDE]
    float*  ws    = (float*)d_ws;
    float2* ed    = (float2*)ws;
    float2* ed2   = (float2*)(ws + (size_t)2 * E);
    float*  h     = ws + (size_t)4 * E;
    float4* pp    = (float4*)(h + (size_t)N * 64);
    int*    base  = (int*)(h + (size_t)N * 64 + (size_t)N * 4);
    int*    bbase = base + (N + 1);
    int*    bcnt  = bbase + (NB + 1);
    int*    bcur  = bcnt + (size_t)NB * CSTRIDE;

    hipLaunchKernelGGL(z0_zero, dim3((NB + 255) / 256), dim3(256), 0, stream, bcnt, NB);
    hipLaunchKernelGGL(k1_proj, dim3((N + 15) / 16), dim3(256), 0, stream,
                       feat, wfc, wpost, bpost, h, pp, N);
    hipLaunchKernelGGL(k2_bhist, dim3((E + 255) / 256), dim3(256), 0, stream, dst, bcnt, E);
    hipLaunchKernelGGL(bscan, dim3(1), dim3(256), 0, stream, bcnt, bbase, bcur, base, NB, N);
    hipLaunchKernelGGL(k4_scatter, dim3((E + 255) / 256), dim3(256), 0, stream,
                       src, dst, noise, pp, bcur, ed, E);
    hipLaunchKernelGGL(k4_sort, dim3(NB), dim3(256), 0, stream, bbase, ed, ed2, base, N);
    long k5_threads = (long)N * 64;
    hipLaunchKernelGGL(k5_node, dim3((unsigned)((k5_threads + 255) / 256)), dim3(256), 0, stream,
                       base, ed2, (const float4*)h, (const float4*)bias, (float4*)d_out, N);
}

// Round 8
// 428.659 us; speedup vs baseline: 1.3723x; 1.0126x over previous
//
#include <hip/hip_runtime.h>
#include <math.h>

#define NSLOPE 0.2f
#define CAP 4096          // max edges per 64-node bucket handled in LDS
#define CSTRIDE 16        // counter stride in ints (64B: one line per counter)
#define NPART 8           // XCD partitions per bucket (blockIdx & 7)

// ---------------- Z0: zero per-(bucket,part) counters ----------------
__global__ __launch_bounds__(256) void z0_zero(int* __restrict__ bcnt, int nctr) {
    int i = blockIdx.x * 256 + threadIdx.x;
    if (i < nctr) bcnt[i * CSTRIDE] = 0;
}

// ---------------- K1: h = feat @ W_fc, fused pp = h @ W_post + b_post ----------------
// 256 thr = 4 waves; 32 rows/block (8 rows/wave); lane = output col; K staged in 2 phases
__global__ __launch_bounds__(256) void k1_proj(
    const float* __restrict__ feat, const float* __restrict__ wfc,
    const float* __restrict__ wpost, const float* __restrict__ bpost,
    float* __restrict__ h, float4* __restrict__ pp, int n)
{
    __shared__ float wfc_s[64 * 64];    // 16 KB (one K-phase of W)
    __shared__ float feat_s[32 * 128];  // 16 KB
    int t = threadIdx.x;
    int row0 = blockIdx.x * 32;
    {
        const float4* fv = (const float4*)(feat + (long)row0 * 128);
        int lim = (n - row0) * 32;            // float4s = rows*32
        if (lim > 1024) lim = 1024;
        for (int i = t; i < lim; i += 256)
            ((float4*)feat_s)[i] = fv[i];
    }
    int lane = t & 63, wv = t >> 6;
    const float* fr = feat_s + wv * 8 * 128;
    float acc[8] = {0.f, 0.f, 0.f, 0.f, 0.f, 0.f, 0.f, 0.f};
    #pragma unroll
    for (int p = 0; p < 2; p++) {
        __syncthreads();                      // prev phase done before W overwrite
        const float4* wsrc = ((const float4*)wfc) + p * 1024;
        for (int i = t; i < 1024; i += 256)
            ((float4*)wfc_s)[i] = wsrc[i];
        __syncthreads();
        const float* fp = fr + p * 64;
        #pragma unroll 2
        for (int kk = 0; kk < 64; kk += 4) {
            float w0 = wfc_s[(kk + 0) * 64 + lane];  // 2-way alias: free
            float w1 = wfc_s[(kk + 1) * 64 + lane];
            float w2 = wfc_s[(kk + 2) * 64 + lane];
            float w3 = wfc_s[(kk + 3) * 64 + lane];
            #pragma unroll
            for (int r = 0; r < 8; r++) {
                float4 f = *(const float4*)(fp + r * 128 + kk);  // b128 broadcast
                acc[r] += f.x * w0 + f.y * w1 + f.z * w2 + f.w * w3;
            }
        }
    }
    int r0 = row0 + wv * 8;
    #pragma unroll
    for (int r = 0; r < 8; r++)
        if (r0 + r < n) h[(long)(r0 + r) * 64 + lane] = acc[r];
    // pp epilogue: wave-wide reduction, lane = h-column
    float4 wp = ((const float4*)wpost)[lane];
    float4 bp = *((const float4*)bpost);
    #pragma unroll
    for (int r = 0; r < 8; r++) {
        float cx = acc[r] * wp.x, cy = acc[r] * wp.y,
              cz = acc[r] * wp.z, cw = acc[r] * wp.w;
        #pragma unroll
        for (int off = 32; off > 0; off >>= 1) {
            cx += __shfl_down(cx, off);
            cy += __shfl_down(cy, off);
            cz += __shfl_down(cz, off);
            cw += __shfl_down(cw, off);
        }
        if (lane == 0 && r0 + r < n) {
            float4 o;
            o.x = cx + bp.x; o.y = cy + bp.y; o.z = cz + bp.z; o.w = cw + bp.w;
            pp[r0 + r] = o;
        }
    }
}

// ---------------- K2: per-(bucket,part) histogram ----------------
__global__ __launch_bounds__(256) void k2_bhist(const int* __restrict__ dst,
                                                int* __restrict__ bcnt, int E) {
    int e = blockIdx.x * 256 + threadIdx.x;
    int part = blockIdx.x & (NPART - 1);
    if (e < E) atomicAdd(&bcnt[((dst[e] >> 6) * NPART + part) * CSTRIDE], 1);
}

// ---------------- BSCAN: single-block exclusive scan over NB*NPART entries ----------------
__global__ __launch_bounds__(256) void bscan(const int* __restrict__ bcnt,
                                             int* __restrict__ bbase,
                                             int* __restrict__ bcur,
                                             int* __restrict__ base,
                                             int nent, int NB, int N) {
    __shared__ int lds[256];
    int t = threadIdx.x;
    int per = (nent + 255) >> 8;
    int s0 = t * per;
    int sum = 0;
    for (int k = 0; k < per; k++) {
        int i = s0 + k;
        if (i < nent) sum += bcnt[i * CSTRIDE];
    }
    lds[t] = sum;
    __syncthreads();
    for (int off = 1; off < 256; off <<= 1) {
        int v = (t >= off) ? lds[t - off] : 0;
        __syncthreads();
        lds[t] += v;
        __syncthreads();
    }
    int run = t ? lds[t - 1] : 0;
    for (int k = 0; k < per; k++) {
        int i = s0 + k;
        if (i < nent) {
            if ((i & (NPART - 1)) == 0) bbase[i / NPART] = run;  // bucket start
            bcur[i * CSTRIDE] = run;
            run += bcnt[i * CSTRIDE];
        }
    }
    if (t == 255) { bbase[NB] = lds[255]; base[N] = lds[255]; }
}

// ---------------- K4a: edge value + XCD-partitioned bucket append ----------------
__global__ __launch_bounds__(256) void k4_scatter(
    const int* __restrict__ src, const int* __restrict__ dst,
    const float* __restrict__ noise, const float4* __restrict__ pp,
    int* __restrict__ bcur, float2* __restrict__ ed, int E)
{
    int e = blockIdx.x * 256 + threadIdx.x;
    int part = blockIdx.x & (NPART - 1);
    if (e >= E) return;
    int s = src[e], d = dst[e];
    float4 ps = pp[s], pd = pp[d];
    float loc = ps.x + pd.y;
    loc = loc >= 0.f ? loc : NSLOPE * loc;
    float ev = loc + __expf(ps.z + pd.w) * noise[e];
    int pos = atomicAdd(&bcur[((d >> 6) * NPART + part) * CSTRIDE], 1);
    float2 v; v.x = ev;
    v.y = __uint_as_float((unsigned)s | ((unsigned)(d & 63) << 26));
    ed[pos] = v;        // append region private to this XCD partition
}

// ---------------- K4b: per-bucket LDS counting sort + softmax-normalize + base ----------------
__global__ __launch_bounds__(256) void k4_sort(
    const int* __restrict__ bbase, const float2* __restrict__ ed,
    float2* __restrict__ ed2, int* __restrict__ base, int N)
{
    __shared__ float    s_ev[CAP];
    __shared__ unsigned s_pk[CAP];
    __shared__ float    o_ev[CAP];
    __shared__ unsigned o_sr[CAP];
    __shared__ int c[64], ox[64], c2[64];
    int t = threadIdx.x;
    int b = blockIdx.x;
    int n0 = b << 6;
    int nn = N - n0; if (nn > 64) nn = 64;
    int gb = bbase[b], cnt = bbase[b + 1] - gb;
    if (t < 64) { c[t] = 0; c2[t] = 0; }
    __syncthreads();
    if (cnt <= CAP) {
        for (int i = t; i < cnt; i += 256) {
            float2 v = ed[gb + i];
            unsigned pk = __float_as_uint(v.y);
            s_ev[i] = v.x; s_pk[i] = pk;
            atomicAdd(&c[pk >> 26], 1);
        }
        __syncthreads();
        if (t < 64) {
            int val = c[t], inc = val;
            #pragma unroll
            for (int off = 1; off < 64; off <<= 1) {
                int u = __shfl_up(inc, off);
                if (t >= off) inc += u;
            }
            ox[t] = inc - val;
            if (t < nn) base[n0 + t] = gb + inc - val;   // per-node CSR base
        }
        __syncthreads();
        for (int i = t; i < cnt; i += 256) {
            unsigned pk = s_pk[i];
            int dl = pk >> 26;
            int p = ox[dl] + atomicAdd(&c2[dl], 1);
            o_ev[p] = s_ev[i];
            o_sr[p] = pk & 0x03FFFFFFu;
        }
        __syncthreads();
        if (t < 64 && t < nn) {     // per-node softmax normalize in LDS
            int i0 = ox[t], i1 = i0 + c[t];
            float m = -INFINITY;
            for (int i = i0; i < i1; i++) m = fmaxf(m, o_ev[i]);
            float ssum = 0.f;
            for (int i = i0; i < i1; i++) { float w = __expf(o_ev[i] - m); o_ev[i] = w; ssum += w; }
            float inv = 1.f / ssum;
            for (int i = i0; i < i1; i++) o_ev[i] *= inv;
        }
        __syncthreads();
        for (int i = t; i < cnt; i += 256) {
            float2 v; v.x = o_ev[i]; v.y = __uint_as_float(o_sr[i]);
            ed2[gb + i] = v;
        }
    } else {
        // fallback for oversized buckets (never for this input)
        for (int i = t; i < cnt; i += 256)
            atomicAdd(&c[__float_as_uint(ed[gb + i].y) >> 26], 1);
        __syncthreads();
        if (t < 64) {
            int val = c[t], inc = val;
            #pragma unroll
            for (int off = 1; off < 64; off <<= 1) {
                int u = __shfl_up(inc, off);
                if (t >= off) inc += u;
            }
            ox[t] = inc - val;
            if (t < nn) base[n0 + t] = gb + inc - val;
        }
        __syncthreads();
        for (int i = t; i < cnt; i += 256) {
            float2 v = ed[gb + i];
            unsigned pk = __float_as_uint(v.y);
            int dl = pk >> 26;
            int p = ox[dl] + atomicAdd(&c2[dl], 1);
            float2 o; o.x = v.x; o.y = __uint_as_float(pk & 0x03FFFFFFu);
            ed2[gb + p] = o;
        }
        __syncthreads();
        __threadfence();
        if (t < 64 && t < nn) {
            int i0 = gb + ox[t], i1 = i0 + c[t];
            float m = -INFINITY;
            for (int i = i0; i < i1; i++) m = fmaxf(m, ed2[i].x);
            float ssum = 0.f;
            for (int i = i0; i < i1; i++) ssum += __expf(ed2[i].x - m);
            float inv = 1.f / ssum;
            for (int i = i0; i < i1; i++) {
                float2 v = ed2[i];
                v.x = __expf(v.x - m) * inv;
                ed2[i] = v;
            }
        }
    }
}

// ---------------- K5: pure normalized-weighted gather-sum ----------------
__global__ __launch_bounds__(256) void k5_node(
    const int* __restrict__ base, const float2* __restrict__ ed2,
    const float4* __restrict__ h4, const float4* __restrict__ bias4,
    float4* __restrict__ out4, int N)
{
    int wid = (int)((blockIdx.x * 256 + threadIdx.x) >> 6);
    int lane = threadIdx.x & 63;
    if (wid >= N) return;
    int c = lane & 15, sub = lane >> 4;
    int b0 = base[wid], b1 = base[wid + 1];
    float4 a0 = {0.f, 0.f, 0.f, 0.f}, a1 = {0.f, 0.f, 0.f, 0.f};
    int jb = b0;
    for (; jb + 8 <= b1; jb += 8) {
        float2 e0 = ed2[jb + sub];
        float2 e1 = ed2[jb + 4 + sub];
        float4 v0 = h4[(long)__float_as_int(e0.y) * 16 + c];
        float4 v1 = h4[(long)__float_as_int(e1.y) * 16 + c];
        a0.x += e0.x * v0.x; a0.y += e0.x * v0.y; a0.z += e0.x * v0.z; a0.w += e0.x * v0.w;
        a1.x += e1.x * v1.x; a1.y += e1.x * v1.y; a1.z += e1.x * v1.z; a1.w += e1.x * v1.w;
    }
    for (; jb < b1; jb += 4) {
        int jj = jb + sub;
        float w = 0.f; int s = 0;
        if (jj < b1) { float2 e = ed2[jj]; w = e.x; s = __float_as_int(e.y); }
        float4 v = h4[(long)s * 16 + c];
        a0.x += w * v.x; a0.y += w * v.y; a0.z += w * v.z; a0.w += w * v.w;
    }
    a0.x += a1.x; a0.y += a1.y; a0.z += a1.z; a0.w += a1.w;
    a0.x += __shfl_xor(a0.x, 16); a0.y += __shfl_xor(a0.y, 16);
    a0.z += __shfl_xor(a0.z, 16); a0.w += __shfl_xor(a0.w, 16);
    a0.x += __shfl_xor(a0.x, 32); a0.y += __shfl_xor(a0.y, 32);
    a0.z += __shfl_xor(a0.z, 32); a0.w += __shfl_xor(a0.w, 32);
    if (sub == 0) {
        float4 bp = bias4[c];
        float4 o;
        o.x = a0.x + bp.x; o.y = a0.y + bp.y; o.z = a0.z + bp.z; o.w = a0.w + bp.w;
        out4[(long)wid * 16 + c] = o;
    }
}

extern "C" void kernel_launch(void* const* d_in, const int* in_sizes, int n_in,
                              void* d_out, int out_size, void* d_ws, size_t ws_size,
                              hipStream_t stream) {
    const float* feat  = (const float*)d_in[0];
    const float* wfc   = (const float*)d_in[1];
    const float* wpost = (const float*)d_in[2];
    const float* bpost = (const float*)d_in[3];
    const float* bias  = (const float*)d_in[4];
    const float* noise = (const float*)d_in[5];
    const int*   src   = (const int*)d_in[6];
    const int*   dst   = (const int*)d_in[7];
    int N = in_sizes[0] / 128;
    int E = in_sizes[6];
    int NB = (N + 63) / 64;
    int nent = NB * NPART;

    // ws (4B units): ed[2E] | ed2[2E] | h[N*64] | pp[N*4] | base[N+1] |
    //                bbase[NB+1] | bcnt[nent*CSTRIDE] | bcur[nent*CSTRIDE]
    float*  ws    = (float*)d_ws;
    float2* ed    = (float2*)ws;
    float2* ed2   = (float2*)(ws + (size_t)2 * E);
    float*  h     = ws + (size_t)4 * E;
    float4* pp    = (float4*)(h + (size_t)N * 64);
    int*    base  = (int*)(h + (size_t)N * 64 + (size_t)N * 4);
    int*    bbase = base + (N + 1);
    int*    bcnt  = bbase + (NB + 1);
    int*    bcur  = bcnt + (size_t)nent * CSTRIDE;

    hipLaunchKernelGGL(z0_zero, dim3((nent + 255) / 256), dim3(256), 0, stream, bcnt, nent);
    hipLaunchKernelGGL(k1_proj, dim3((N + 31) / 32), dim3(256), 0, stream,
                       feat, wfc, wpost, bpost, h, pp, N);
    hipLaunchKernelGGL(k2_bhist, dim3((E + 255) / 256), dim3(256), 0, stream, dst, bcnt, E);
    hipLaunchKernelGGL(bscan, dim3(1), dim3(256), 0, stream,
                       bcnt, bbase, bcur, base, nent, NB, N);
    hipLaunchKernelGGL(k4_scatter, dim3((E + 255) / 256), dim3(256), 0, stream,
                       src, dst, noise, pp, bcur, ed, E);
    hipLaunchKernelGGL(k4_sort, dim3(NB), dim3(256), 0, stream, bbase, ed, ed2, base, N);
    long k5_threads = (long)N * 64;
    hipLaunchKernelGGL(k5_node, dim3((unsigned)((k5_threads + 255) / 256)), dim3(256), 0, stream,
                       base, ed2, (const float4*)h, (const float4*)bias, (float4*)d_out, N);
}

// Round 10
// 389.135 us; speedup vs baseline: 1.5117x; 1.1016x over previous
//
#include <hip/hip_runtime.h>
#include <math.h>

#define NSLOPE 0.2f
#define CAP 4096          // max edges per 64-node bucket handled in LDS
#define CSTRIDE 16        // counter stride in ints (64B: one line per counter)
#define NPART 8           // XCD partitions per bucket (blockIdx & 7)
#define ASTRIDE 136       // bf16 LDS row stride (128 + 8 pad), keeps 16B align

typedef __attribute__((ext_vector_type(8))) short bf16x8;
typedef __attribute__((ext_vector_type(4))) short bf16x4;
typedef __attribute__((ext_vector_type(4))) float f32x4;

__device__ __forceinline__ unsigned short f2bf(float x) {
    unsigned u = __float_as_uint(x);
    u += 0x7fffu + ((u >> 16) & 1u);    // round-to-nearest-even
    return (unsigned short)(u >> 16);
}

// ---------------- Z0: zero per-(bucket,part) counters ----------------
__global__ __launch_bounds__(256) void z0_zero(int* __restrict__ bcnt, int nctr) {
    int i = blockIdx.x * 256 + threadIdx.x;
    if (i < nctr) bcnt[i * CSTRIDE] = 0;
}

// ---------------- KW: Wc = W_fc @ W_post (128x64 @ 64x4 -> 128x4), fp32 ----------------
__global__ __launch_bounds__(128) void kW(const float* __restrict__ wfc,
                                          const float* __restrict__ wpost,
                                          float4* __restrict__ wc) {
    __shared__ float wp_s[256];
    int t = threadIdx.x;
    wp_s[t] = wpost[t];
    wp_s[128 + t] = wpost[128 + t];
    __syncthreads();
    float a0 = 0.f, a1 = 0.f, a2 = 0.f, a3 = 0.f;
    for (int n = 0; n < 64; n++) {
        float w = wfc[t * 64 + n];
        a0 += w * wp_s[n * 4 + 0]; a1 += w * wp_s[n * 4 + 1];
        a2 += w * wp_s[n * 4 + 2]; a3 += w * wp_s[n * 4 + 3];
    }
    float4 o; o.x = a0; o.y = a1; o.z = a2; o.w = a3;
    wc[t] = o;
}

// ---------------- K1: h = feat @ W_fc via bf16 MFMA (h stored bf16) ----------------
// 256 thr = 4 waves; 64 rows/block (16 rows/wave)
__global__ __launch_bounds__(256) void k1_mfma(
    const float* __restrict__ feat, const float* __restrict__ wfc,
    float4* __restrict__ h_g, int n)
{
    __shared__ unsigned short a_s[64 * ASTRIDE];   // feat tile bf16
    __shared__ unsigned short b_s[64 * ASTRIDE];   // W_fc^T bf16
    int t = threadIdx.x;
    int row0 = blockIdx.x * 64;
    // stage A: 64 rows x 128 cols fp32 -> bf16 (zeros for pad rows)
    for (int i = t; i < 2048; i += 256) {
        int row = i >> 5, c4 = (i & 31) * 4;
        float4 f = {0.f, 0.f, 0.f, 0.f};
        if (row0 + row < n) f = ((const float4*)(feat + (long)(row0 + row) * 128))[i & 31];
        bf16x4 b4;
        b4.x = (short)f2bf(f.x); b4.y = (short)f2bf(f.y);
        b4.z = (short)f2bf(f.z); b4.w = (short)f2bf(f.w);
        *(bf16x4*)(a_s + row * ASTRIDE + c4) = b4;
    }
    // stage B = W^T: W[k][n] fp32 (128x64) -> b_s[n][k] bf16
    for (int i = t; i < 2048; i += 256) {
        int k = i >> 4, n0 = (i & 15) * 4;
        float4 f = ((const float4*)wfc)[i];
        b_s[(n0 + 0) * ASTRIDE + k] = f2bf(f.x);
        b_s[(n0 + 1) * ASTRIDE + k] = f2bf(f.y);
        b_s[(n0 + 2) * ASTRIDE + k] = f2bf(f.z);
        b_s[(n0 + 3) * ASTRIDE + k] = f2bf(f.w);
    }
    __syncthreads();
    int lane = t & 63, wv = t >> 6;
    int c = lane & 15, quad = lane >> 4;
    f32x4 acc[4] = {{0.f,0.f,0.f,0.f},{0.f,0.f,0.f,0.f},{0.f,0.f,0.f,0.f},{0.f,0.f,0.f,0.f}};
    int arow = wv * 16 + c;
    #pragma unroll
    for (int kb = 0; kb < 4; kb++) {
        int ko = kb * 32 + quad * 8;
        bf16x8 af = *(const bf16x8*)(a_s + arow * ASTRIDE + ko);
        #pragma unroll
        for (int tt = 0; tt < 4; tt++) {
            bf16x8 bf = *(const bf16x8*)(b_s + (tt * 16 + c) * ASTRIDE + ko);
            acc[tt] = __builtin_amdgcn_mfma_f32_16x16x32_bf16(af, bf, acc[tt], 0, 0, 0);
        }
    }
    // pack C tiles into LDS (reuse a_s) then coalesced bf16 store
    __syncthreads();
    unsigned short* h_s = a_s;   // 64 rows x 64 cols bf16
    #pragma unroll
    for (int tt = 0; tt < 4; tt++)
        #pragma unroll
        for (int r = 0; r < 4; r++)
            h_s[(wv * 16 + quad * 4 + r) * 64 + tt * 16 + c] = f2bf(acc[tt][r]);
    __syncthreads();
    for (int i = t; i < 512; i += 256) {   // 64 rows x 8 float4
        int row = i >> 3;
        if (row0 + row < n)
            h_g[(long)(row0 + row) * 8 + (i & 7)] = *(const float4*)(h_s + row * 64 + (i & 7) * 8);
    }
}

// ---------------- K1b: pp = feat @ Wc + b_post, PURE FP32 (precision-critical) ----------------
// wave per node; lane k covers feat cols k and k+64
__global__ __launch_bounds__(256) void k1b_pp(
    const float* __restrict__ feat, const float4* __restrict__ wc,
    const float* __restrict__ bpost, float4* __restrict__ pp, int N)
{
    int wid = (int)((blockIdx.x * 256 + threadIdx.x) >> 6);
    int lane = threadIdx.x & 63;
    if (wid >= N) return;
    const float* fr = feat + (long)wid * 128;
    float f0 = fr[lane], f1 = fr[64 + lane];
    float4 w0 = wc[lane], w1 = wc[64 + lane];
    float p0 = f0 * w0.x + f1 * w1.x;
    float p1 = f0 * w0.y + f1 * w1.y;
    float p2 = f0 * w0.z + f1 * w1.z;
    float p3 = f0 * w0.w + f1 * w1.w;
    #pragma unroll
    for (int off = 1; off < 64; off <<= 1) {
        p0 += __shfl_xor(p0, off);
        p1 += __shfl_xor(p1, off);
        p2 += __shfl_xor(p2, off);
        p3 += __shfl_xor(p3, off);
    }
    if (lane == 0) {
        float4 bp = *((const float4*)bpost);
        float4 o;
        o.x = p0 + bp.x; o.y = p1 + bp.y; o.z = p2 + bp.z; o.w = p3 + bp.w;
        pp[wid] = o;
    }
}

// ---------------- K2: per-(bucket,part) histogram ----------------
__global__ __launch_bounds__(256) void k2_bhist(const int* __restrict__ dst,
                                                int* __restrict__ bcnt, int E) {
    int e = blockIdx.x * 256 + threadIdx.x;
    int part = blockIdx.x & (NPART - 1);
    if (e < E) atomicAdd(&bcnt[((dst[e] >> 6) * NPART + part) * CSTRIDE], 1);
}

// ---------------- BSCAN: single-block exclusive scan over NB*NPART entries ----------------
__global__ __launch_bounds__(256) void bscan(const int* __restrict__ bcnt,
                                             int* __restrict__ bbase,
                                             int* __restrict__ bcur,
                                             int* __restrict__ base,
                                             int nent, int NB, int N) {
    __shared__ int lds[256];
    int t = threadIdx.x;
    int per = (nent + 255) >> 8;
    int s0 = t * per;
    int sum = 0;
    for (int k = 0; k < per; k++) {
        int i = s0 + k;
        if (i < nent) sum += bcnt[i * CSTRIDE];
    }
    lds[t] = sum;
    __syncthreads();
    for (int off = 1; off < 256; off <<= 1) {
        int v = (t >= off) ? lds[t - off] : 0;
        __syncthreads();
        lds[t] += v;
        __syncthreads();
    }
    int run = t ? lds[t - 1] : 0;
    for (int k = 0; k < per; k++) {
        int i = s0 + k;
        if (i < nent) {
            if ((i & (NPART - 1)) == 0) bbase[i / NPART] = run;
            bcur[i * CSTRIDE] = run;
            run += bcnt[i * CSTRIDE];
        }
    }
    if (t == 255) { bbase[NB] = lds[255]; base[N] = lds[255]; }
}

// ---------------- K4a: edge value + XCD-partitioned bucket append ----------------
__global__ __launch_bounds__(256) void k4_scatter(
    const int* __restrict__ src, const int* __restrict__ dst,
    const float* __restrict__ noise, const float4* __restrict__ pp,
    int* __restrict__ bcur, float2* __restrict__ ed, int E)
{
    int e = blockIdx.x * 256 + threadIdx.x;
    int part = blockIdx.x & (NPART - 1);
    if (e >= E) return;
    int s = src[e], d = dst[e];
    float4 ps = pp[s], pd = pp[d];
    float loc = ps.x + pd.y;
    loc = loc >= 0.f ? loc : NSLOPE * loc;
    float ev = loc + __expf(ps.z + pd.w) * noise[e];
    int pos = atomicAdd(&bcur[((d >> 6) * NPART + part) * CSTRIDE], 1);
    float2 v; v.x = ev;
    v.y = __uint_as_float((unsigned)s | ((unsigned)(d & 63) << 26));
    ed[pos] = v;
}

// ---------------- K4b: per-bucket LDS counting sort + softmax-normalize + base ----------------
__global__ __launch_bounds__(256) void k4_sort(
    const int* __restrict__ bbase, const float2* __restrict__ ed,
    float2* __restrict__ ed2, int* __restrict__ base, int N)
{
    __shared__ float    s_ev[CAP];
    __shared__ unsigned s_pk[CAP];
    __shared__ float    o_ev[CAP];
    __shared__ unsigned o_sr[CAP];
    __shared__ int c[64], ox[64], c2[64];
    int t = threadIdx.x;
    int b = blockIdx.x;
    int n0 = b << 6;
    int nn = N - n0; if (nn > 64) nn = 64;
    int gb = bbase[b], cnt = bbase[b + 1] - gb;
    if (t < 64) { c[t] = 0; c2[t] = 0; }
    __syncthreads();
    if (cnt <= CAP) {
        for (int i = t; i < cnt; i += 256) {
            float2 v = ed[gb + i];
            unsigned pk = __float_as_uint(v.y);
            s_ev[i] = v.x; s_pk[i] = pk;
            atomicAdd(&c[pk >> 26], 1);
        }
        __syncthreads();
        if (t < 64) {
            int val = c[t], inc = val;
            #pragma unroll
            for (int off = 1; off < 64; off <<= 1) {
                int u = __shfl_up(inc, off);
                if (t >= off) inc += u;
            }
            ox[t] = inc - val;
            if (t < nn) base[n0 + t] = gb + inc - val;
        }
        __syncthreads();
        for (int i = t; i < cnt; i += 256) {
            unsigned pk = s_pk[i];
            int dl = pk >> 26;
            int p = ox[dl] + atomicAdd(&c2[dl], 1);
            o_ev[p] = s_ev[i];
            o_sr[p] = pk & 0x03FFFFFFu;
        }
        __syncthreads();
        if (t < 64 && t < nn) {
            int i0 = ox[t], i1 = i0 + c[t];
            float m = -INFINITY;
            for (int i = i0; i < i1; i++) m = fmaxf(m, o_ev[i]);
            float ssum = 0.f;
            for (int i = i0; i < i1; i++) { float w = __expf(o_ev[i] - m); o_ev[i] = w; ssum += w; }
            float inv = 1.f / ssum;
            for (int i = i0; i < i1; i++) o_ev[i] *= inv;
        }
        __syncthreads();
        for (int i = t; i < cnt; i += 256) {
            float2 v; v.x = o_ev[i]; v.y = __uint_as_float(o_sr[i]);
            ed2[gb + i] = v;
        }
    } else {
        for (int i = t; i < cnt; i += 256)
            atomicAdd(&c[__float_as_uint(ed[gb + i].y) >> 26], 1);
        __syncthreads();
        if (t < 64) {
            int val = c[t], inc = val;
            #pragma unroll
            for (int off = 1; off < 64; off <<= 1) {
                int u = __shfl_up(inc, off);
                if (t >= off) inc += u;
            }
            ox[t] = inc - val;
            if (t < nn) base[n0 + t] = gb + inc - val;
        }
        __syncthreads();
        for (int i = t; i < cnt; i += 256) {
            float2 v = ed[gb + i];
            unsigned pk = __float_as_uint(v.y);
            int dl = pk >> 26;
            int p = ox[dl] + atomicAdd(&c2[dl], 1);
            float2 o; o.x = v.x; o.y = __uint_as_float(pk & 0x03FFFFFFu);
            ed2[gb + p] = o;
        }
        __syncthreads();
        __threadfence();
        if (t < 64 && t < nn) {
            int i0 = gb + ox[t], i1 = i0 + c[t];
            float m = -INFINITY;
            for (int i = i0; i < i1; i++) m = fmaxf(m, ed2[i].x);
            float ssum = 0.f;
            for (int i = i0; i < i1; i++) ssum += __expf(ed2[i].x - m);
            float inv = 1.f / ssum;
            for (int i = i0; i < i1; i++) {
                float2 v = ed2[i];
                v.x = __expf(v.x - m) * inv;
                ed2[i] = v;
            }
        }
    }
}

// ---------------- K5: normalized-weighted gather-sum, bf16 h, 8-16 edges in flight ----------------
// wave = node; sub = lane>>3 (edge slot 0..7), c = lane&7 (16B chunk of the 128B row)
__global__ __launch_bounds__(256) void k5_node(
    const int* __restrict__ base, const float2* __restrict__ ed2,
    const uint4* __restrict__ h8, const float* __restrict__ bias,
    float4* __restrict__ out4, int N)
{
    int wid = (int)((blockIdx.x * 256 + threadIdx.x) >> 6);
    int lane = threadIdx.x & 63;
    if (wid >= N) return;
    int c = lane & 7, sub = lane >> 3;
    int b0 = base[wid], b1 = base[wid + 1];
    float a[8] = {0.f,0.f,0.f,0.f,0.f,0.f,0.f,0.f};
    int jb = b0;
    for (; jb + 16 <= b1; jb += 16) {
        float2 e0 = ed2[jb + sub];
        float2 e1 = ed2[jb + 8 + sub];
        uint4 p0 = h8[(long)__float_as_int(e0.y) * 8 + c];
        uint4 p1 = h8[(long)__float_as_int(e1.y) * 8 + c];
        float w0 = e0.x, w1 = e1.x;
        a[0] += w0 * __uint_as_float(p0.x << 16);
        a[1] += w0 * __uint_as_float(p0.x & 0xffff0000u);
        a[2] += w0 * __uint_as_float(p0.y << 16);
        a[3] += w0 * __uint_as_float(p0.y & 0xffff0000u);
        a[4] += w0 * __uint_as_float(p0.z << 16);
        a[5] += w0 * __uint_as_float(p0.z & 0xffff0000u);
        a[6] += w0 * __uint_as_float(p0.w << 16);
        a[7] += w0 * __uint_as_float(p0.w & 0xffff0000u);
        a[0] += w1 * __uint_as_float(p1.x << 16);
        a[1] += w1 * __uint_as_float(p1.x & 0xffff0000u);
        a[2] += w1 * __uint_as_float(p1.y << 16);
        a[3] += w1 * __uint_as_float(p1.y & 0xffff0000u);
        a[4] += w1 * __uint_as_float(p1.z << 16);
        a[5] += w1 * __uint_as_float(p1.z & 0xffff0000u);
        a[6] += w1 * __uint_as_float(p1.w << 16);
        a[7] += w1 * __uint_as_float(p1.w & 0xffff0000u);
    }
    for (; jb < b1; jb += 8) {
        int jj = jb + sub;
        float w = 0.f; int s = 0;
        if (jj < b1) { float2 e = ed2[jj]; w = e.x; s = __float_as_int(e.y); }
        uint4 p = h8[(long)s * 8 + c];
        a[0] += w * __uint_as_float(p.x << 16);
        a[1] += w * __uint_as_float(p.x & 0xffff0000u);
        a[2] += w * __uint_as_float(p.y << 16);
        a[3] += w * __uint_as_float(p.y & 0xffff0000u);
        a[4] += w * __uint_as_float(p.z << 16);
        a[5] += w * __uint_as_float(p.z & 0xffff0000u);
        a[6] += w * __uint_as_float(p.w << 16);
        a[7] += w * __uint_as_float(p.w & 0xffff0000u);
    }
    #pragma unroll
    for (int off = 8; off < 64; off <<= 1)
        #pragma unroll
        for (int i = 0; i < 8; i++) a[i] += __shfl_xor(a[i], off);
    if (sub == 0) {
        float4 o0, o1;
        const float* bl = bias + c * 8;
        o0.x = a[0] + bl[0]; o0.y = a[1] + bl[1]; o0.z = a[2] + bl[2]; o0.w = a[3] + bl[3];
        o1.x = a[4] + bl[4]; o1.y = a[5] + bl[5]; o1.z = a[6] + bl[6]; o1.w = a[7] + bl[7];
        out4[(long)wid * 16 + c * 2]     = o0;
        out4[(long)wid * 16 + c * 2 + 1] = o1;
    }
}

extern "C" void kernel_launch(void* const* d_in, const int* in_sizes, int n_in,
                              void* d_out, int out_size, void* d_ws, size_t ws_size,
                              hipStream_t stream) {
    const float* feat  = (const float*)d_in[0];
    const float* wfc   = (const float*)d_in[1];
    const float* wpost = (const float*)d_in[2];
    const float* bpost = (const float*)d_in[3];
    const float* bias  = (const float*)d_in[4];
    const float* noise = (const float*)d_in[5];
    const int*   src   = (const int*)d_in[6];
    const int*   dst   = (const int*)d_in[7];
    int N = in_sizes[0] / 128;
    int E = in_sizes[6];
    int NB = (N + 63) / 64;
    int nent = NB * NPART;

    // ws (4B units): ed[2E] | ed2[2E] | h_bf16[N*32] | pp[N*4] | base[N+1] |
    //                bbase[NB+1] | bcnt[nent*CSTRIDE] | bcur[nent*CSTRIDE] | wc[512]
    float*  ws    = (float*)d_ws;
    float2* ed    = (float2*)ws;
    float2* ed2   = (float2*)(ws + (size_t)2 * E);
    float*  h     = ws + (size_t)4 * E;            // N*64 bf16 = N*32 floats
    float4* pp    = (float4*)(h + (size_t)N * 32);
    int*    base  = (int*)(h + (size_t)N * 32 + (size_t)N * 4);
    int*    bbase = base + (N + 1);
    int*    bcnt  = bbase + (NB + 1);
    int*    bcur  = bcnt + (size_t)nent * CSTRIDE;
    float4* wc    = (float4*)(bcur + (size_t)nent * CSTRIDE);

    hipLaunchKernelGGL(z0_zero, dim3((nent + 255) / 256), dim3(256), 0, stream, bcnt, nent);
    hipLaunchKernelGGL(kW, dim3(1), dim3(128), 0, stream, wfc, wpost, wc);
    hipLaunchKernelGGL(k1_mfma, dim3((N + 63) / 64), dim3(256), 0, stream,
                       feat, wfc, (float4*)h, N);
    hipLaunchKernelGGL(k1b_pp, dim3((N + 3) / 4), dim3(256), 0, stream,
                       feat, wc, bpost, pp, N);
    hipLaunchKernelGGL(k2_bhist, dim3((E + 255) / 256), dim3(256), 0, stream, dst, bcnt, E);
    hipLaunchKernelGGL(bscan, dim3(1), dim3(256), 0, stream,
                       bcnt, bbase, bcur, base, nent, NB, N);
    hipLaunchKernelGGL(k4_scatter, dim3((E + 255) / 256), dim3(256), 0, stream,
                       src, dst, noise, pp, bcur, ed, E);
    hipLaunchKernelGGL(k4_sort, dim3(NB), dim3(256), 0, stream, bbase, ed, ed2, base, N);
    long k5_threads = (long)N * 64;
    hipLaunchKernelGGL(k5_node, dim3((unsigned)((k5_threads + 255) / 256)), dim3(256), 0, stream,
                       base, ed2, (const uint4*)h, bias, (float4*)d_out, N);
}